// Round 16
// baseline (207.632 us; speedup 1.0000x reference)
//
#include <hip/hip_runtime.h>
#include <hip/hip_bf16.h>
#include <math.h>

typedef __bf16 bf16x8 __attribute__((ext_vector_type(8)));
typedef float f32x4 __attribute__((ext_vector_type(4)));

// QSCALE * log2(e): Q (and the bias tables derived from Q) live in the exp2
// domain, so softmax needs only exp2f.
#define QSCALE_L2E (0.08838834764831845f * 1.4426950408889634f)

static __device__ __forceinline__ unsigned short bits_bf16(float v) {
  __hip_bfloat16 h = __float2bfloat16(v);
  return *reinterpret_cast<unsigned short*>(&h);
}

// async global->LDS DMA, 16B per lane; LDS dest = wave-uniform base + lane*16
static __device__ __forceinline__ void gload16(const void* g, void* l) {
  __builtin_amdgcn_global_load_lds(
      (const __attribute__((address_space(1))) void*)g,
      (__attribute__((address_space(3))) void*)l, 16, 0, 0);
}

// ---------------- kernel 1: convert weights + rel tables to bf16 ----------------
__global__ __launch_bounds__(256) void k_convw(const float* __restrict__ wqk,
                                               const float* __restrict__ wv,
                                               const float* __restrict__ relw,
                                               const float* __restrict__ relh,
                                               __hip_bfloat16* __restrict__ wall,
                                               __hip_bfloat16* __restrict__ relsb) {
  int i = blockIdx.x * 256 + threadIdx.x;
  if (i < 1536 * 512) {
    float v = (i < 1024 * 512) ? wqk[i] : wv[i - 1024 * 512];
    wall[i] = __float2bfloat16(v);
  } else {
    int j = i - 1536 * 512;  // 0..16383 : [2][64][128], row 63 of each table = 0
    int t = j >> 13, m = (j >> 7) & 63, d = j & 127;
    float v = (m < 63) ? (t ? relh[m * 128 + d] : relw[m * 128 + d]) : 0.f;
    relsb[j] = __float2bfloat16(v);
  }
}

// ---------------- kernel 2: transpose + convert featuremap -> [B][L][C] bf16 ----------------
__global__ __launch_bounds__(256) void k_tfm(const float* __restrict__ fm,
                                             __hip_bfloat16* __restrict__ fmt) {
  __shared__ float t[64][65];
  int lt = blockIdx.x, ct = blockIdx.y, b = blockIdx.z;
  int tid = threadIdx.x;
  const float* src = fm + ((size_t)b * 512 + ct * 64) * 1024 + lt * 64;
#pragma unroll
  for (int i = 0; i < 16; ++i) {
    int idx = i * 256 + tid;
    int r = idx >> 6, cl = idx & 63;
    t[r][cl] = src[(size_t)r * 1024 + cl];
  }
  __syncthreads();
  __hip_bfloat16* dst = fmt + ((size_t)b * 1024 + lt * 64) * 512 + ct * 64;
#pragma unroll
  for (int i = 0; i < 16; ++i) {
    int idx = i * 256 + tid;
    int r = idx >> 6, cc = idx & 63;
    dst[(size_t)r * 512 + cc] = __float2bfloat16(t[cc][r]);
  }
}

// ---------------- kernel 3: QKV projection GEMM (m97 structure) ----------------
__global__ __launch_bounds__(256) void k_gemm(const __hip_bfloat16* __restrict__ fmt,
                                              const __hip_bfloat16* __restrict__ wall,
                                              __hip_bfloat16* __restrict__ Qb,
                                              __hip_bfloat16* __restrict__ Kb,
                                              __hip_bfloat16* __restrict__ Vt) {
  __shared__ char smem[32768];
  char* As = smem;
  char* Bs = smem + 16384;
  int bm = blockIdx.x, bn = blockIdx.y, b = blockIdx.z;
  int tid = threadIdx.x;
  int lane = tid & 63, wave = tid >> 6;
  int wr = wave >> 1, wc = wave & 1;
  int g = lane >> 4, ln = lane & 15;
  const char* Ag = (const char*)(fmt + ((size_t)b * 1024 + bm * 128) * 512);
  const char* Bg = (const char*)(wall + (size_t)bn * 128 * 512);

  int j3 = lane >> 3, j7 = lane & 7;
  int segsrc = ((j7 ^ j3) << 4);  // pre-swizzled source seg (row&7 == j3)

  f32x4 acc[4][4] = {};
  for (int kb = 0; kb < 8; ++kb) {
#pragma unroll
    for (int i = 0; i < 4; ++i) {
      int R = (wave * 4 + i) * 8;  // 8 rows per 1KB DMA
      size_t go = (size_t)(R + j3) * 1024 + (size_t)kb * 128 + segsrc;
      gload16(Ag + go, As + R * 128);
      gload16(Bg + go, Bs + R * 128);
    }
    __syncthreads();
#pragma unroll
    for (int ks = 0; ks < 2; ++ks) {
      int kcol = ks * 64 + (g << 4);
      bf16x8 af[4], bfr[4];
#pragma unroll
      for (int m = 0; m < 4; ++m) {
        int row = wr * 64 + m * 16 + ln;
        af[m] = *(const bf16x8*)(As + row * 128 + (kcol ^ ((ln & 7) << 4)));
      }
#pragma unroll
      for (int n = 0; n < 4; ++n) {
        int row = wc * 64 + n * 16 + ln;
        bfr[n] = *(const bf16x8*)(Bs + row * 128 + (kcol ^ ((ln & 7) << 4)));
      }
#pragma unroll
      for (int m = 0; m < 4; ++m)
#pragma unroll
        for (int n = 0; n < 4; ++n)
          acc[m][n] = __builtin_amdgcn_mfma_f32_16x16x32_bf16(af[m], bfr[n], acc[m][n], 0, 0, 0);
    }
    __syncthreads();
  }

  // ---- epilogue: restage C tile in LDS, then coalesced row stores ----
  int otype = bn >> 2;  // 0=q, 1=k, 2=v
  int head = bn & 3;
  if (otype != 2) {
    float sc = (otype == 0) ? QSCALE_L2E : 1.0f;
#pragma unroll
    for (int m = 0; m < 4; ++m)
#pragma unroll
      for (int n = 0; n < 4; ++n) {
        int d = wc * 64 + n * 16 + ln;
#pragma unroll
        for (int r = 0; r < 4; ++r) {
          int l = wr * 64 + m * 16 + g * 4 + r;
          *(__hip_bfloat16*)(smem + l * 256 + ((d * 2) ^ ((l & 7) << 4))) =
              __float2bfloat16(acc[m][n][r] * sc);
        }
      }
    __syncthreads();
    __hip_bfloat16* dstb =
        (otype == 0 ? Qb : Kb) + (((size_t)(b * 4 + head) * 1024) + bm * 128) * 128;
#pragma unroll
    for (int i = 0; i < 8; ++i) {
      int idx = i * 256 + tid;
      int row = idx >> 4, c16 = idx & 15;
      uint4 v = *(const uint4*)(smem + row * 256 + ((c16 * 16) ^ ((row & 7) << 4)));
      *(uint4*)(dstb + (size_t)row * 128 + c16 * 8) = v;
    }
  } else {
#pragma unroll
    for (int m = 0; m < 4; ++m)
#pragma unroll
      for (int n = 0; n < 4; ++n) {
        int d = wc * 64 + n * 16 + ln;
        int lbase = wr * 64 + m * 16 + g * 4;
        ushort4 pk;
        pk.x = bits_bf16(acc[m][n][0]);
        pk.y = bits_bf16(acc[m][n][1]);
        pk.z = bits_bf16(acc[m][n][2]);
        pk.w = bits_bf16(acc[m][n][3]);
        *(ushort4*)(smem + d * 256 + ((lbase * 2) ^ ((d & 7) << 4))) = pk;
      }
    __syncthreads();
    __hip_bfloat16* dstb = Vt + ((size_t)(b * 4 + head) * 128) * 1024 + bm * 128;
#pragma unroll
    for (int i = 0; i < 8; ++i) {
      int idx = i * 256 + tid;
      int row = idx >> 4, c16 = idx & 15;
      uint4 v = *(const uint4*)(smem + row * 256 + ((c16 * 16) ^ ((row & 7) << 4)));
      *(uint4*)(dstb + (size_t)row * 1024 + c16 * 8) = v;
    }
  }
}

// ---------------- kernel 4: bias tables via MFMA ----------------
// Tables inherit the log2e factor from Qb automatically.
__global__ __launch_bounds__(256) void k_bias(const __hip_bfloat16* __restrict__ Qb,
                                              const __hip_bfloat16* __restrict__ relsb,
                                              float* __restrict__ QRW,
                                              float* __restrict__ QRH) {
  __shared__ char sh[32768];  // [2][64][128] bf16, swizzled
  int bx = blockIdx.x, bh = blockIdx.y;
  int tid = threadIdx.x, lane = tid & 63, wave = tid >> 6;
  int g = lane >> 4, ln = lane & 15;
#pragma unroll
  for (int i = 0; i < 8; ++i) {
    int chunk = i * 256 + tid;
    int row = chunk >> 4, c16 = chunk & 15;
    *(uint4*)(sh + row * 256 + ((c16 * 16) ^ ((row & 7) << 4))) =
        *(const uint4*)(relsb + (size_t)row * 128 + c16 * 8);
  }
  __syncthreads();
  size_t bhL = (size_t)bh * 1024;
  int l0 = bx * 128 + wave * 32;
  const __hip_bfloat16* Qg = Qb + (bhL + l0) * 128;
  bf16x8 a[2][4];
#pragma unroll
  for (int lf = 0; lf < 2; ++lf)
#pragma unroll
    for (int ks = 0; ks < 4; ++ks)
      a[lf][ks] = *(const bf16x8*)(Qg + (size_t)(lf * 16 + ln) * 128 + ks * 32 + g * 8);
#pragma unroll
  for (int t = 0; t < 2; ++t) {
    float* dst = (t == 0 ? QRW : QRH) + (bhL + l0) * 64;
#pragma unroll
    for (int n = 0; n < 4; ++n) {
      f32x4 acc2[2] = {};
#pragma unroll
      for (int ks = 0; ks < 4; ++ks) {
        int mrow = n * 16 + ln;
        bf16x8 bf = *(const bf16x8*)(sh + t * 16384 + mrow * 256 +
                                     ((ks * 64 + g * 16) ^ ((mrow & 7) << 4)));
#pragma unroll
        for (int lf = 0; lf < 2; ++lf)
          acc2[lf] = __builtin_amdgcn_mfma_f32_16x16x32_bf16(a[lf][ks], bf, acc2[lf], 0, 0, 0);
      }
#pragma unroll
      for (int lf = 0; lf < 2; ++lf)
#pragma unroll
        for (int r = 0; r < 4; ++r)
          dst[(size_t)(lf * 16 + g * 4 + r) * 64 + n * 16 + ln] = acc2[lf][r];
    }
  }
}

// ---------------- kernel 5: fused attention (V direct from L1/L2, batched) ----------------
// r15 post-mortem: the V-direct idea was starved by the 64-VGPR cap that
// __launch_bounds__(512,4) imposes (min-BLOCKS semantics: 4 blk x 8 waves =
// 32 waves/CU -> 64 VGPR) -> serial load->use chains, ~200cy L2 latency fully
// exposed. Fix: (512,2) -> 128-VGPR cap (16 waves/CU target, LDS 49K*2 fits),
// and batch all 8 av loads per ks2 into registers BEFORE the MFMA chain so
// one latency covers the batch. DS ops stay 22/wave-kt (vs r14's 38).
__global__ __launch_bounds__(512, 2) void k_attn(const __hip_bfloat16* __restrict__ Qb,
                                                 const __hip_bfloat16* __restrict__ Kb,
                                                 const __hip_bfloat16* __restrict__ Vt,
                                                 const float* __restrict__ QRW,
                                                 const float* __restrict__ QRH,
                                                 float* __restrict__ out) {
  extern __shared__ char smem[];
  char* kb0 = smem;                 // K buf A [64][256B] 16384
  char* kb1 = smem + 16384;         // K buf B 16384
  char* pt = smem + 32768;          // P [8 waves][16 q][128B] 16384
                                    // total 49152 B -> 2 blocks/CU (98K LDS)

  int bh = blockIdx.x, qt = blockIdx.y;  // same-bh blocks: ids differ by 64 -> same XCD
  int b = bh >> 2, h = bh & 3;
  int tid = threadIdx.x, lane = tid & 63, wave = tid >> 6;  // wave 0..7
  int g = lane >> 4, ln = lane & 15;
  int q0 = qt * 128;
  size_t bhL = (size_t)bh * 1024;

  // per-lane q (16 q/wave): one-time global->reg loads
  int qloc = wave * 16 + ln;
  int qg = q0 + qloc;
  int cx = qg & 31, rx = qg >> 5;
  bf16x8 qa[4];
  const __hip_bfloat16* qrow = Qb + (bhL + qg) * 128;
#pragma unroll
  for (int ks = 0; ks < 4; ++ks) qa[ks] = *(const bf16x8*)(qrow + ks * 32 + g * 8);
  float wb[2][4];
  const float* wrow = QRW + (bhL + qg) * 64 + (31 - cx) + g * 4;
#pragma unroll
  for (int half = 0; half < 2; ++half)
#pragma unroll
    for (int r = 0; r < 4; ++r) wb[half][r] = wrow[half * 16 + r];
  const float* hptr = QRH + (bhL + qg) * 64 + (31 - rx);

  const char* Kg0 = (const char*)(Kb + bhL * 128);
  const __hip_bfloat16* Vg0 = Vt + (size_t)bh * 128 * 1024;

  auto STAGE_K = [&](char* kvb, int kt2) {
    const char* Kg = Kg0 + (size_t)kt2 * 64 * 256;
#pragma unroll
    for (int i = 0; i < 2; ++i) {
      int R = (wave * 2 + i) * 4;  // row&7 = 4i + (lane>>4)
      int seg = ((lane & 15) ^ ((i & 1) * 4 + (lane >> 4))) << 4;
      gload16(Kg + (size_t)(R + (lane >> 4)) * 256 + seg, kvb + R * 256);
    }
  };

  f32x4 acc[8] = {};
  float mrow = -1e30f, lrow = 0.f;
  char* pw = pt + wave * 2048;

  STAGE_K(kb0, 0);
  __syncthreads();  // tile 0 ready

  char *kc = kb0, *kn = kb1;

#pragma unroll 1
  for (int kt = 0; kt < 16; ++kt) {
    if (kt < 15) STAGE_K(kn, kt + 1);
    // hb scalars for this kt (global, L2-hot), issued before QK^T
    float hb0 = hptr[kt * 2], hb1 = hptr[kt * 2 + 1];

    // S^T = K Q^T (log2 domain): s[n][r] = S[key=n*16+g*4+r][q=qloc]
    f32x4 s[4] = {};
    __builtin_amdgcn_s_setprio(1);
#pragma unroll
    for (int ks = 0; ks < 4; ++ks) {
      int kcol = ks * 64 + (g << 4);
#pragma unroll
      for (int n = 0; n < 4; ++n) {
        int krow = n * 16 + ln;
        bf16x8 kf = *(const bf16x8*)(kc + krow * 256 + (kcol ^ ((krow & 7) << 4)));
        s[n] = __builtin_amdgcn_mfma_f32_16x16x32_bf16(kf, qa[ks], s[n], 0, 0, 0);
      }
    }
    __builtin_amdgcn_s_setprio(0);

    // bias + online softmax (defer-rescale, THR=8 in exp2 domain)
#pragma unroll
    for (int n = 0; n < 4; ++n) {
      float hb = (n >> 1) ? hb1 : hb0;
#pragma unroll
      for (int r = 0; r < 4; ++r) s[n][r] += wb[n & 1][r] + hb;
    }
    float mt = s[0][0];
#pragma unroll
    for (int n = 0; n < 4; ++n)
#pragma unroll
      for (int r = 0; r < 4; ++r) mt = fmaxf(mt, s[n][r]);
    mt = fmaxf(mt, __shfl_xor(mt, 16, 64));
    mt = fmaxf(mt, __shfl_xor(mt, 32, 64));
    if (__any(mt > mrow + 8.f)) {
      float mn = fmaxf(mrow, mt);
      float alpha = exp2f(mrow - mn);
      mrow = mn;
      lrow *= alpha;
#pragma unroll
      for (int mf = 0; mf < 8; ++mf) acc[mf] *= alpha;
    }
    float rs = 0.f;
#pragma unroll
    for (int n = 0; n < 4; ++n)
#pragma unroll
      for (int r = 0; r < 4; ++r) {
        s[n][r] = exp2f(s[n][r] - mrow);
        rs += s[n][r];
      }
    rs += __shfl_xor(rs, 16, 64);
    rs += __shfl_xor(rs, 32, 64);
    lrow += rs;

    // write P[q=qloc][key] packed (r8-verified layout)
#pragma unroll
    for (int n = 0; n < 4; ++n) {
      ushort4 pk;
      pk.x = bits_bf16(s[n][0]);
      pk.y = bits_bf16(s[n][1]);
      pk.z = bits_bf16(s[n][2]);
      pk.w = bits_bf16(s[n][3]);
      *(ushort4*)(pw + ln * 128 + ((n * 32 + g * 8) ^ ((ln & 7) << 4))) = pk;
    }
    // PV (transposed): acc[d][q] += V_t . P^T ; av batched from global (L1-hot,
    // shared by all 8 waves; 64 lanes = 16 full 64B lines per instr). Batch all
    // 8 loads before the MFMA chain so one L2 latency covers the batch.
    __builtin_amdgcn_s_setprio(1);
#pragma unroll
    for (int ks2 = 0; ks2 < 2; ++ks2) {
      int kcb = ks2 * 64 + (g << 4);
      bf16x8 pb = *(const bf16x8*)(pw + ln * 128 + (kcb ^ ((ln & 7) << 4)));
      const __hip_bfloat16* Vg = Vg0 + kt * 64 + ks2 * 32 + g * 8;
      bf16x8 av[8];
#pragma unroll
      for (int mf = 0; mf < 8; ++mf)
        av[mf] = *(const bf16x8*)(Vg + (size_t)(mf * 16 + ln) * 1024);
#pragma unroll
      for (int mf = 0; mf < 8; ++mf)
        acc[mf] = __builtin_amdgcn_mfma_f32_16x16x32_bf16(av[mf], pb, acc[mf], 0, 0, 0);
    }
    __builtin_amdgcn_s_setprio(0);

    __syncthreads();  // drains next-tile K DMA; releases cur K buffer
    char* t = kc; kc = kn; kn = t;
  }

  // normalize + store (l and acc columns are in-lane)
  float linv = 1.0f / lrow;
#pragma unroll
  for (int mf = 0; mf < 8; ++mf) {
    int dbase = mf * 16 + g * 4;
#pragma unroll
    for (int r = 0; r < 4; ++r) {
      out[((size_t)(b * 512 + h * 128 + dbase + r)) * 1024 + qg] = acc[mf][r] * linv;
    }
  }
}

extern "C" void kernel_launch(void* const* d_in, const int* in_sizes, int n_in,
                              void* d_out, int out_size, void* d_ws, size_t ws_size,
                              hipStream_t stream) {
  const float* fm = (const float*)d_in[0];
  const float* wqk = (const float*)d_in[1];
  const float* wv = (const float*)d_in[2];
  const float* relh = (const float*)d_in[3];
  const float* relw = (const float*)d_in[4];
  float* out = (float*)d_out;
  char* w = (char*)d_ws;

  __hip_bfloat16* fmt = (__hip_bfloat16*)w;                   // 16 MB  [B][L][C]
  __hip_bfloat16* wall = (__hip_bfloat16*)(w + 16777216);     // 1.5 MB [1536][512]
  __hip_bfloat16* Qb = (__hip_bfloat16*)(w + 18350080);       // 16 MB  [B][H][L][D] (scaled*log2e)
  __hip_bfloat16* Kb = (__hip_bfloat16*)(w + 35127296);       // 16 MB  [B][H][L][D]
  __hip_bfloat16* Vt = (__hip_bfloat16*)(w + 51904512);       // 16 MB  [B][H][D][L]
  float* QRW = (float*)(w + 68681728);                        // 16 MB  [B][H][L][64]
  float* QRH = (float*)(w + 85458944);                        // 16 MB  [B][H][L][64]
  __hip_bfloat16* relsb = (__hip_bfloat16*)(w + 102236160);   // 32 KB  [2][64][128]

  hipFuncSetAttribute((const void*)k_attn,
                      hipFuncAttributeMaxDynamicSharedMemorySize, 49152);

  k_convw<<<3136, 256, 0, stream>>>(wqk, wv, relw, relh, wall, relsb);
  k_tfm<<<dim3(16, 8, 16), 256, 0, stream>>>(fm, fmt);
  k_gemm<<<dim3(8, 12, 16), 256, 0, stream>>>(fmt, wall, Qb, Kb, Vt);
  k_bias<<<dim3(8, 64), 256, 0, stream>>>(Qb, relsb, QRW, QRH);
  k_attn<<<dim3(64, 8), 512, 49152, stream>>>(Qb, Kb, Vt, QRW, QRH, out);
}

// Round 17
// 144.704 us; speedup vs baseline: 1.4349x; 1.4349x over previous
//
#include <hip/hip_runtime.h>
#include <hip/hip_bf16.h>
#include <math.h>

typedef __bf16 bf16x8 __attribute__((ext_vector_type(8)));
typedef float f32x4 __attribute__((ext_vector_type(4)));

// QSCALE * log2(e): Q (and the bias tables derived from Q) live in the exp2
// domain, so softmax needs only exp2f.
#define QSCALE_L2E (0.08838834764831845f * 1.4426950408889634f)

static __device__ __forceinline__ unsigned short bits_bf16(float v) {
  __hip_bfloat16 h = __float2bfloat16(v);
  return *reinterpret_cast<unsigned short*>(&h);
}

// async global->LDS DMA, 16B per lane; LDS dest = wave-uniform base + lane*16
static __device__ __forceinline__ void gload16(const void* g, void* l) {
  __builtin_amdgcn_global_load_lds(
      (const __attribute__((address_space(1))) void*)g,
      (__attribute__((address_space(3))) void*)l, 16, 0, 0);
}

// ---------------- kernel 1: convert weights + rel tables to bf16 ----------------
__global__ __launch_bounds__(256) void k_convw(const float* __restrict__ wqk,
                                               const float* __restrict__ wv,
                                               const float* __restrict__ relw,
                                               const float* __restrict__ relh,
                                               __hip_bfloat16* __restrict__ wall,
                                               __hip_bfloat16* __restrict__ relsb) {
  int i = blockIdx.x * 256 + threadIdx.x;
  if (i < 1536 * 512) {
    float v = (i < 1024 * 512) ? wqk[i] : wv[i - 1024 * 512];
    wall[i] = __float2bfloat16(v);
  } else {
    int j = i - 1536 * 512;  // 0..16383 : [2][64][128], row 63 of each table = 0
    int t = j >> 13, m = (j >> 7) & 63, d = j & 127;
    float v = (m < 63) ? (t ? relh[m * 128 + d] : relw[m * 128 + d]) : 0.f;
    relsb[j] = __float2bfloat16(v);
  }
}

// ---------------- kernel 2: transpose + convert featuremap -> [B][L][C] bf16 ----------------
__global__ __launch_bounds__(256) void k_tfm(const float* __restrict__ fm,
                                             __hip_bfloat16* __restrict__ fmt) {
  __shared__ float t[64][65];
  int lt = blockIdx.x, ct = blockIdx.y, b = blockIdx.z;
  int tid = threadIdx.x;
  const float* src = fm + ((size_t)b * 512 + ct * 64) * 1024 + lt * 64;
#pragma unroll
  for (int i = 0; i < 16; ++i) {
    int idx = i * 256 + tid;
    int r = idx >> 6, cl = idx & 63;
    t[r][cl] = src[(size_t)r * 1024 + cl];
  }
  __syncthreads();
  __hip_bfloat16* dst = fmt + ((size_t)b * 1024 + lt * 64) * 512 + ct * 64;
#pragma unroll
  for (int i = 0; i < 16; ++i) {
    int idx = i * 256 + tid;
    int r = idx >> 6, cc = idx & 63;
    dst[(size_t)r * 512 + cc] = __float2bfloat16(t[cc][r]);
  }
}

// ---------------- kernel 3: QKV projection GEMM (m97 structure) + fused bias tables ----------------
// Q-type blocks additionally compute QRW/QRH[l][m] = Q[l].rel[m] from the
// already-staged LDS Q tile (A-fragments from swizzled smem; B-fragments from
// L2-hot relsb) -- eliminates the separate k_bias kernel and its 16MB Q re-read.
__global__ __launch_bounds__(256) void k_gemm(const __hip_bfloat16* __restrict__ fmt,
                                              const __hip_bfloat16* __restrict__ wall,
                                              const __hip_bfloat16* __restrict__ relsb,
                                              __hip_bfloat16* __restrict__ Qb,
                                              __hip_bfloat16* __restrict__ Kb,
                                              __hip_bfloat16* __restrict__ Vt,
                                              float* __restrict__ QRW,
                                              float* __restrict__ QRH) {
  __shared__ char smem[32768];
  char* As = smem;
  char* Bs = smem + 16384;
  int bm = blockIdx.x, bn = blockIdx.y, b = blockIdx.z;
  int tid = threadIdx.x;
  int lane = tid & 63, wave = tid >> 6;
  int wr = wave >> 1, wc = wave & 1;
  int g = lane >> 4, ln = lane & 15;
  const char* Ag = (const char*)(fmt + ((size_t)b * 1024 + bm * 128) * 512);
  const char* Bg = (const char*)(wall + (size_t)bn * 128 * 512);

  int j3 = lane >> 3, j7 = lane & 7;
  int segsrc = ((j7 ^ j3) << 4);  // pre-swizzled source seg (row&7 == j3)

  f32x4 acc[4][4] = {};
  for (int kb = 0; kb < 8; ++kb) {
#pragma unroll
    for (int i = 0; i < 4; ++i) {
      int R = (wave * 4 + i) * 8;  // 8 rows per 1KB DMA
      size_t go = (size_t)(R + j3) * 1024 + (size_t)kb * 128 + segsrc;
      gload16(Ag + go, As + R * 128);
      gload16(Bg + go, Bs + R * 128);
    }
    __syncthreads();
#pragma unroll
    for (int ks = 0; ks < 2; ++ks) {
      int kcol = ks * 64 + (g << 4);
      bf16x8 af[4], bfr[4];
#pragma unroll
      for (int m = 0; m < 4; ++m) {
        int row = wr * 64 + m * 16 + ln;
        af[m] = *(const bf16x8*)(As + row * 128 + (kcol ^ ((ln & 7) << 4)));
      }
#pragma unroll
      for (int n = 0; n < 4; ++n) {
        int row = wc * 64 + n * 16 + ln;
        bfr[n] = *(const bf16x8*)(Bs + row * 128 + (kcol ^ ((ln & 7) << 4)));
      }
#pragma unroll
      for (int m = 0; m < 4; ++m)
#pragma unroll
        for (int n = 0; n < 4; ++n)
          acc[m][n] = __builtin_amdgcn_mfma_f32_16x16x32_bf16(af[m], bfr[n], acc[m][n], 0, 0, 0);
    }
    __syncthreads();
  }

  // ---- epilogue: restage C tile in LDS, then coalesced row stores ----
  int otype = bn >> 2;  // 0=q, 1=k, 2=v
  int head = bn & 3;
  if (otype != 2) {
    float sc = (otype == 0) ? QSCALE_L2E : 1.0f;
#pragma unroll
    for (int m = 0; m < 4; ++m)
#pragma unroll
      for (int n = 0; n < 4; ++n) {
        int d = wc * 64 + n * 16 + ln;
#pragma unroll
        for (int r = 0; r < 4; ++r) {
          int l = wr * 64 + m * 16 + g * 4 + r;
          *(__hip_bfloat16*)(smem + l * 256 + ((d * 2) ^ ((l & 7) << 4))) =
              __float2bfloat16(acc[m][n][r] * sc);
        }
      }
    __syncthreads();
    __hip_bfloat16* dstb =
        (otype == 0 ? Qb : Kb) + (((size_t)(b * 4 + head) * 1024) + bm * 128) * 128;
#pragma unroll
    for (int i = 0; i < 8; ++i) {
      int idx = i * 256 + tid;
      int row = idx >> 4, c16 = idx & 15;
      uint4 v = *(const uint4*)(smem + row * 256 + ((c16 * 16) ^ ((row & 7) << 4)));
      *(uint4*)(dstb + (size_t)row * 128 + c16 * 8) = v;
    }
    if (otype == 0) {
      // ---- fused bias tables (identical math to the former k_bias) ----
      // A-fragments from the swizzled LDS Q tile (holds Qb's exact bf16 values,
      // already scaled by QSCALE_L2E); B-fragments from global relsb (L2-hot).
      int lf0 = wave * 32;  // each of the 4 waves handles 32 l-rows
      bf16x8 a2[2][4];
#pragma unroll
      for (int lf = 0; lf < 2; ++lf)
#pragma unroll
        for (int ks = 0; ks < 4; ++ks) {
          int row = lf0 + lf * 16 + ln;
          a2[lf][ks] = *(const bf16x8*)(smem + row * 256 +
                                        ((ks * 64 + g * 16) ^ ((row & 7) << 4)));
        }
#pragma unroll
      for (int t = 0; t < 2; ++t) {
        float* dst = (t == 0 ? QRW : QRH) +
                     (((size_t)(b * 4 + head) * 1024) + bm * 128 + lf0) * 64;
#pragma unroll
        for (int n = 0; n < 4; ++n) {
          f32x4 acc2[2] = {};
#pragma unroll
          for (int ks = 0; ks < 4; ++ks) {
            int mrow = n * 16 + ln;
            bf16x8 bf =
                *(const bf16x8*)(relsb + t * 8192 + mrow * 128 + ks * 32 + g * 8);
#pragma unroll
            for (int lf = 0; lf < 2; ++lf)
              acc2[lf] =
                  __builtin_amdgcn_mfma_f32_16x16x32_bf16(a2[lf][ks], bf, acc2[lf], 0, 0, 0);
          }
#pragma unroll
          for (int lf = 0; lf < 2; ++lf)
#pragma unroll
            for (int r = 0; r < 4; ++r)
              dst[(size_t)(lf * 16 + g * 4 + r) * 64 + n * 16 + ln] = acc2[lf][r];
        }
      }
    }
  } else {
#pragma unroll
    for (int m = 0; m < 4; ++m)
#pragma unroll
      for (int n = 0; n < 4; ++n) {
        int d = wc * 64 + n * 16 + ln;
        int lbase = wr * 64 + m * 16 + g * 4;
        ushort4 pk;
        pk.x = bits_bf16(acc[m][n][0]);
        pk.y = bits_bf16(acc[m][n][1]);
        pk.z = bits_bf16(acc[m][n][2]);
        pk.w = bits_bf16(acc[m][n][3]);
        *(ushort4*)(smem + d * 256 + ((lbase * 2) ^ ((d & 7) << 4))) = pk;
      }
    __syncthreads();
    __hip_bfloat16* dstb = Vt + ((size_t)(b * 4 + head) * 128) * 1024 + bm * 128;
#pragma unroll
    for (int i = 0; i < 8; ++i) {
      int idx = i * 256 + tid;
      int row = idx >> 4, c16 = idx & 15;
      uint4 v = *(const uint4*)(smem + row * 256 + ((c16 * 16) ^ ((row & 7) << 4)));
      *(uint4*)(dstb + (size_t)row * 1024 + c16 * 8) = v;
    }
  }
}

// ---------------- kernel 5: fused attention (r14-exact: V in LDS, 16 q/wave) ----------------
// r15/r16 post-mortem: V-direct-from-global is starved by the VGPR budget at
// 16 waves/CU (allocator lands at 60-64 VGPR; no room to batch av loads ->
// serialized ~200cy L2 latency, 151-155us). r14's LDS-V at 67us is the proven
// best: 16 q/wave, 8 waves, K+V double-buffered via global_load_lds, 2 blocks/CU.
__global__ __launch_bounds__(512, 4) void k_attn(const __hip_bfloat16* __restrict__ Qb,
                                                 const __hip_bfloat16* __restrict__ Kb,
                                                 const __hip_bfloat16* __restrict__ Vt,
                                                 const float* __restrict__ QRW,
                                                 const float* __restrict__ QRH,
                                                 float* __restrict__ out) {
  extern __shared__ char smem[];
  char* kb0 = smem;                 // K buf A [64][256B] 16384
  char* kb1 = smem + 16384;         // K buf B 16384
  char* vb0 = smem + 32768;         // V buf A [128][128B] 16384
  char* vb1 = smem + 49152;         // V buf B 16384
  char* pt = smem + 65536;          // P [8 waves][16 q][128B] 16384
                                    // total 81920 B -> 2 blocks/CU (160K exactly)

  int bh = blockIdx.x, qt = blockIdx.y;  // same-bh blocks: ids differ by 64 -> same XCD
  int b = bh >> 2, h = bh & 3;
  int tid = threadIdx.x, lane = tid & 63, wave = tid >> 6;  // wave 0..7
  int g = lane >> 4, ln = lane & 15;
  int q0 = qt * 128;
  size_t bhL = (size_t)bh * 1024;

  // per-lane q (16 q/wave): one-time global->reg loads
  int qloc = wave * 16 + ln;
  int qg = q0 + qloc;
  int cx = qg & 31, rx = qg >> 5;
  bf16x8 qa[4];
  const __hip_bfloat16* qrow = Qb + (bhL + qg) * 128;
#pragma unroll
  for (int ks = 0; ks < 4; ++ks) qa[ks] = *(const bf16x8*)(qrow + ks * 32 + g * 8);
  float wb[2][4];
  const float* wrow = QRW + (bhL + qg) * 64 + (31 - cx) + g * 4;
#pragma unroll
  for (int half = 0; half < 2; ++half)
#pragma unroll
    for (int r = 0; r < 4; ++r) wb[half][r] = wrow[half * 16 + r];
  const float* hptr = QRH + (bhL + qg) * 64 + (31 - rx);

  const char* Kg0 = (const char*)(Kb + bhL * 128);
  const char* Vg0 = (const char*)(Vt + (size_t)bh * 128 * 1024);
  int j3 = lane >> 3, j7 = lane & 7;
  int segv = ((j7 ^ j3) << 4);

  auto STAGE_K = [&](char* kvb, int kt2) {
    const char* Kg = Kg0 + (size_t)kt2 * 64 * 256;
#pragma unroll
    for (int i = 0; i < 2; ++i) {
      int R = (wave * 2 + i) * 4;  // row&7 = 4i + (lane>>4)
      int seg = ((lane & 15) ^ ((i & 1) * 4 + (lane >> 4))) << 4;
      gload16(Kg + (size_t)(R + (lane >> 4)) * 256 + seg, kvb + R * 256);
    }
  };
  auto STAGE_V = [&](char* vtb, int kt2) {
    const char* Vg = Vg0 + (size_t)kt2 * 128;
#pragma unroll
    for (int i = 0; i < 2; ++i) {
      int R = (wave * 2 + i) * 8;
      gload16(Vg + (size_t)(R + j3) * 2048 + segv, vtb + R * 128);
    }
  };

  f32x4 acc[8] = {};
  float mrow = -1e30f, lrow = 0.f;
  char* pw = pt + wave * 2048;

  STAGE_K(kb0, 0);
  STAGE_V(vb0, 0);
  __syncthreads();  // tile 0 ready

  char *kc = kb0, *kn = kb1, *vc = vb0, *vn = vb1;

#pragma unroll 1
  for (int kt = 0; kt < 16; ++kt) {
    if (kt < 15) {
      STAGE_K(kn, kt + 1);
      STAGE_V(vn, kt + 1);
    }
    // hb scalars for this kt (global, L2-hot), issued before QK^T
    float hb0 = hptr[kt * 2], hb1 = hptr[kt * 2 + 1];

    // S^T = K Q^T (log2 domain): s[n][r] = S[key=n*16+g*4+r][q=qloc]
    f32x4 s[4] = {};
    __builtin_amdgcn_s_setprio(1);
#pragma unroll
    for (int ks = 0; ks < 4; ++ks) {
      int kcol = ks * 64 + (g << 4);
#pragma unroll
      for (int n = 0; n < 4; ++n) {
        int krow = n * 16 + ln;
        bf16x8 kf = *(const bf16x8*)(kc + krow * 256 + (kcol ^ ((krow & 7) << 4)));
        s[n] = __builtin_amdgcn_mfma_f32_16x16x32_bf16(kf, qa[ks], s[n], 0, 0, 0);
      }
    }
    __builtin_amdgcn_s_setprio(0);

    // bias + online softmax (defer-rescale, THR=8 in exp2 domain)
#pragma unroll
    for (int n = 0; n < 4; ++n) {
      float hb = (n >> 1) ? hb1 : hb0;
#pragma unroll
      for (int r = 0; r < 4; ++r) s[n][r] += wb[n & 1][r] + hb;
    }
    float mt = s[0][0];
#pragma unroll
    for (int n = 0; n < 4; ++n)
#pragma unroll
      for (int r = 0; r < 4; ++r) mt = fmaxf(mt, s[n][r]);
    mt = fmaxf(mt, __shfl_xor(mt, 16, 64));
    mt = fmaxf(mt, __shfl_xor(mt, 32, 64));
    if (__any(mt > mrow + 8.f)) {
      float mn = fmaxf(mrow, mt);
      float alpha = exp2f(mrow - mn);
      mrow = mn;
      lrow *= alpha;
#pragma unroll
      for (int mf = 0; mf < 8; ++mf) acc[mf] *= alpha;
    }
    float rs = 0.f;
#pragma unroll
    for (int n = 0; n < 4; ++n)
#pragma unroll
      for (int r = 0; r < 4; ++r) {
        s[n][r] = exp2f(s[n][r] - mrow);
        rs += s[n][r];
      }
    rs += __shfl_xor(rs, 16, 64);
    rs += __shfl_xor(rs, 32, 64);
    lrow += rs;

    // write P[q=qloc][key] packed (r8-verified layout)
#pragma unroll
    for (int n = 0; n < 4; ++n) {
      ushort4 pk;
      pk.x = bits_bf16(s[n][0]);
      pk.y = bits_bf16(s[n][1]);
      pk.z = bits_bf16(s[n][2]);
      pk.w = bits_bf16(s[n][3]);
      *(ushort4*)(pw + ln * 128 + ((n * 32 + g * 8) ^ ((ln & 7) << 4))) = pk;
    }
    // PV (transposed): acc[d][q] += V_t . P^T
    __builtin_amdgcn_s_setprio(1);
#pragma unroll
    for (int ks2 = 0; ks2 < 2; ++ks2) {
      int kcb = ks2 * 64 + (g << 4);
      bf16x8 pb = *(const bf16x8*)(pw + ln * 128 + (kcb ^ ((ln & 7) << 4)));
#pragma unroll
      for (int mf = 0; mf < 8; ++mf) {
        int vrow = mf * 16 + ln;
        bf16x8 av = *(const bf16x8*)(vc + vrow * 128 + (kcb ^ ((vrow & 7) << 4)));
        acc[mf] = __builtin_amdgcn_mfma_f32_16x16x32_bf16(av, pb, acc[mf], 0, 0, 0);
      }
    }
    __builtin_amdgcn_s_setprio(0);

    __syncthreads();  // drains next-tile DMA; releases cur buffers
    char* t = kc; kc = kn; kn = t;
    char* t2 = vc; vc = vn; vn = t2;
  }

  // normalize + store (l and acc columns are in-lane)
  float linv = 1.0f / lrow;
#pragma unroll
  for (int mf = 0; mf < 8; ++mf) {
    int dbase = mf * 16 + g * 4;
#pragma unroll
    for (int r = 0; r < 4; ++r) {
      out[((size_t)(b * 512 + h * 128 + dbase + r)) * 1024 + qg] = acc[mf][r] * linv;
    }
  }
}

extern "C" void kernel_launch(void* const* d_in, const int* in_sizes, int n_in,
                              void* d_out, int out_size, void* d_ws, size_t ws_size,
                              hipStream_t stream) {
  const float* fm = (const float*)d_in[0];
  const float* wqk = (const float*)d_in[1];
  const float* wv = (const float*)d_in[2];
  const float* relh = (const float*)d_in[3];
  const float* relw = (const float*)d_in[4];
  float* out = (float*)d_out;
  char* w = (char*)d_ws;

  __hip_bfloat16* fmt = (__hip_bfloat16*)w;                   // 16 MB  [B][L][C]
  __hip_bfloat16* wall = (__hip_bfloat16*)(w + 16777216);     // 1.5 MB [1536][512]
  __hip_bfloat16* Qb = (__hip_bfloat16*)(w + 18350080);       // 16 MB  [B][H][L][D] (scaled*log2e)
  __hip_bfloat16* Kb = (__hip_bfloat16*)(w + 35127296);       // 16 MB  [B][H][L][D]
  __hip_bfloat16* Vt = (__hip_bfloat16*)(w + 51904512);       // 16 MB  [B][H][D][L]
  float* QRW = (float*)(w + 68681728);                        // 16 MB  [B][H][L][64]
  float* QRH = (float*)(w + 85458944);                        // 16 MB  [B][H][L][64]
  __hip_bfloat16* relsb = (__hip_bfloat16*)(w + 102236160);   // 32 KB  [2][64][128]

  hipFuncSetAttribute((const void*)k_attn,
                      hipFuncAttributeMaxDynamicSharedMemorySize, 81920);

  k_convw<<<3136, 256, 0, stream>>>(wqk, wv, relw, relh, wall, relsb);
  k_tfm<<<dim3(16, 8, 16), 256, 0, stream>>>(fm, fmt);
  k_gemm<<<dim3(8, 12, 16), 256, 0, stream>>>(fmt, wall, relsb, Qb, Kb, Vt, QRW, QRH);
  k_attn<<<dim3(64, 8), 512, 81920, stream>>>(Qb, Kb, Vt, QRW, QRH, out);
}

// Round 18
// 121.837 us; speedup vs baseline: 1.7042x; 1.1877x over previous
//
#include <hip/hip_runtime.h>
#include <hip/hip_bf16.h>
#include <math.h>

typedef __bf16 bf16x8 __attribute__((ext_vector_type(8)));
typedef float f32x4 __attribute__((ext_vector_type(4)));

// QSCALE * log2(e): Q (and the bias tables derived from Q) live in the exp2
// domain, so softmax needs only exp2f.
#define QSCALE_L2E (0.08838834764831845f * 1.4426950408889634f)

static __device__ __forceinline__ unsigned short bits_bf16(float v) {
  __hip_bfloat16 h = __float2bfloat16(v);
  return *reinterpret_cast<unsigned short*>(&h);
}

// async global->LDS DMA, 16B per lane; LDS dest = wave-uniform base + lane*16
static __device__ __forceinline__ void gload16(const void* g, void* l) {
  __builtin_amdgcn_global_load_lds(
      (const __attribute__((address_space(1))) void*)g,
      (__attribute__((address_space(3))) void*)l, 16, 0, 0);
}

// ---------------- kernel 1: convert weights + rel tables to bf16 ----------------
__global__ __launch_bounds__(256) void k_convw(const float* __restrict__ wqk,
                                               const float* __restrict__ wv,
                                               const float* __restrict__ relw,
                                               const float* __restrict__ relh,
                                               __hip_bfloat16* __restrict__ wall,
                                               __hip_bfloat16* __restrict__ relsb) {
  int i = blockIdx.x * 256 + threadIdx.x;
  if (i < 1536 * 512) {
    float v = (i < 1024 * 512) ? wqk[i] : wv[i - 1024 * 512];
    wall[i] = __float2bfloat16(v);
  } else {
    int j = i - 1536 * 512;  // 0..16383 : [2][64][128], row 63 of each table = 0
    int t = j >> 13, m = (j >> 7) & 63, d = j & 127;
    float v = (m < 63) ? (t ? relh[m * 128 + d] : relw[m * 128 + d]) : 0.f;
    relsb[j] = __float2bfloat16(v);
  }
}

// ---------------- kernel 2: transpose + convert featuremap -> [B][L][C] bf16 ----------------
__global__ __launch_bounds__(256) void k_tfm(const float* __restrict__ fm,
                                             __hip_bfloat16* __restrict__ fmt) {
  __shared__ float t[64][65];
  int lt = blockIdx.x, ct = blockIdx.y, b = blockIdx.z;
  int tid = threadIdx.x;
  const float* src = fm + ((size_t)b * 512 + ct * 64) * 1024 + lt * 64;
#pragma unroll
  for (int i = 0; i < 16; ++i) {
    int idx = i * 256 + tid;
    int r = idx >> 6, cl = idx & 63;
    t[r][cl] = src[(size_t)r * 1024 + cl];
  }
  __syncthreads();
  __hip_bfloat16* dst = fmt + ((size_t)b * 1024 + lt * 64) * 512 + ct * 64;
#pragma unroll
  for (int i = 0; i < 16; ++i) {
    int idx = i * 256 + tid;
    int r = idx >> 6, cc = idx & 63;
    dst[(size_t)r * 512 + cc] = __float2bfloat16(t[cc][r]);
  }
}

// ---------------- kernel 3: QKV projection GEMM (m97 structure) ----------------
// NOTE (r17 post-mortem): do NOT fuse the bias-table GEMM into this kernel's
// Q-epilogue — it raises the common-path VGPR high-water mark (88->140), drops
// occupancy to ~10%, and the m97 structure loses the implicit multi-block
// overlap that hides its barrier drain (30us -> 89us measured).
__global__ __launch_bounds__(256) void k_gemm(const __hip_bfloat16* __restrict__ fmt,
                                              const __hip_bfloat16* __restrict__ wall,
                                              __hip_bfloat16* __restrict__ Qb,
                                              __hip_bfloat16* __restrict__ Kb,
                                              __hip_bfloat16* __restrict__ Vt) {
  __shared__ char smem[32768];
  char* As = smem;
  char* Bs = smem + 16384;
  int bm = blockIdx.x, bn = blockIdx.y, b = blockIdx.z;
  int tid = threadIdx.x;
  int lane = tid & 63, wave = tid >> 6;
  int wr = wave >> 1, wc = wave & 1;
  int g = lane >> 4, ln = lane & 15;
  const char* Ag = (const char*)(fmt + ((size_t)b * 1024 + bm * 128) * 512);
  const char* Bg = (const char*)(wall + (size_t)bn * 128 * 512);

  int j3 = lane >> 3, j7 = lane & 7;
  int segsrc = ((j7 ^ j3) << 4);  // pre-swizzled source seg (row&7 == j3)

  f32x4 acc[4][4] = {};
  for (int kb = 0; kb < 8; ++kb) {
#pragma unroll
    for (int i = 0; i < 4; ++i) {
      int R = (wave * 4 + i) * 8;  // 8 rows per 1KB DMA
      size_t go = (size_t)(R + j3) * 1024 + (size_t)kb * 128 + segsrc;
      gload16(Ag + go, As + R * 128);
      gload16(Bg + go, Bs + R * 128);
    }
    __syncthreads();
#pragma unroll
    for (int ks = 0; ks < 2; ++ks) {
      int kcol = ks * 64 + (g << 4);
      bf16x8 af[4], bfr[4];
#pragma unroll
      for (int m = 0; m < 4; ++m) {
        int row = wr * 64 + m * 16 + ln;
        af[m] = *(const bf16x8*)(As + row * 128 + (kcol ^ ((ln & 7) << 4)));
      }
#pragma unroll
      for (int n = 0; n < 4; ++n) {
        int row = wc * 64 + n * 16 + ln;
        bfr[n] = *(const bf16x8*)(Bs + row * 128 + (kcol ^ ((ln & 7) << 4)));
      }
#pragma unroll
      for (int m = 0; m < 4; ++m)
#pragma unroll
        for (int n = 0; n < 4; ++n)
          acc[m][n] = __builtin_amdgcn_mfma_f32_16x16x32_bf16(af[m], bfr[n], acc[m][n], 0, 0, 0);
    }
    __syncthreads();
  }

  // ---- epilogue: restage C tile in LDS, then coalesced row stores ----
  int otype = bn >> 2;  // 0=q, 1=k, 2=v
  int head = bn & 3;
  if (otype != 2) {
    float sc = (otype == 0) ? QSCALE_L2E : 1.0f;
#pragma unroll
    for (int m = 0; m < 4; ++m)
#pragma unroll
      for (int n = 0; n < 4; ++n) {
        int d = wc * 64 + n * 16 + ln;
#pragma unroll
        for (int r = 0; r < 4; ++r) {
          int l = wr * 64 + m * 16 + g * 4 + r;
          *(__hip_bfloat16*)(smem + l * 256 + ((d * 2) ^ ((l & 7) << 4))) =
              __float2bfloat16(acc[m][n][r] * sc);
        }
      }
    __syncthreads();
    __hip_bfloat16* dstb =
        (otype == 0 ? Qb : Kb) + (((size_t)(b * 4 + head) * 1024) + bm * 128) * 128;
#pragma unroll
    for (int i = 0; i < 8; ++i) {
      int idx = i * 256 + tid;
      int row = idx >> 4, c16 = idx & 15;
      uint4 v = *(const uint4*)(smem + row * 256 + ((c16 * 16) ^ ((row & 7) << 4)));
      *(uint4*)(dstb + (size_t)row * 128 + c16 * 8) = v;
    }
  } else {
#pragma unroll
    for (int m = 0; m < 4; ++m)
#pragma unroll
      for (int n = 0; n < 4; ++n) {
        int d = wc * 64 + n * 16 + ln;
        int lbase = wr * 64 + m * 16 + g * 4;
        ushort4 pk;
        pk.x = bits_bf16(acc[m][n][0]);
        pk.y = bits_bf16(acc[m][n][1]);
        pk.z = bits_bf16(acc[m][n][2]);
        pk.w = bits_bf16(acc[m][n][3]);
        *(ushort4*)(smem + d * 256 + ((lbase * 2) ^ ((d & 7) << 4))) = pk;
      }
    __syncthreads();
    __hip_bfloat16* dstb = Vt + ((size_t)(b * 4 + head) * 128) * 1024 + bm * 128;
#pragma unroll
    for (int i = 0; i < 8; ++i) {
      int idx = i * 256 + tid;
      int row = idx >> 4, c16 = idx & 15;
      uint4 v = *(const uint4*)(smem + row * 256 + ((c16 * 16) ^ ((row & 7) << 4)));
      *(uint4*)(dstb + (size_t)row * 1024 + c16 * 8) = v;
    }
  }
}

// ---------------- kernel 4: bias tables via MFMA ----------------
// Tables inherit the log2e factor from Qb automatically.
__global__ __launch_bounds__(256) void k_bias(const __hip_bfloat16* __restrict__ Qb,
                                              const __hip_bfloat16* __restrict__ relsb,
                                              float* __restrict__ QRW,
                                              float* __restrict__ QRH) {
  __shared__ char sh[32768];  // [2][64][128] bf16, swizzled
  int bx = blockIdx.x, bh = blockIdx.y;
  int tid = threadIdx.x, lane = tid & 63, wave = tid >> 6;
  int g = lane >> 4, ln = lane & 15;
#pragma unroll
  for (int i = 0; i < 8; ++i) {
    int chunk = i * 256 + tid;
    int row = chunk >> 4, c16 = chunk & 15;
    *(uint4*)(sh + row * 256 + ((c16 * 16) ^ ((row & 7) << 4))) =
        *(const uint4*)(relsb + (size_t)row * 128 + c16 * 8);
  }
  __syncthreads();
  size_t bhL = (size_t)bh * 1024;
  int l0 = bx * 128 + wave * 32;
  const __hip_bfloat16* Qg = Qb + (bhL + l0) * 128;
  bf16x8 a[2][4];
#pragma unroll
  for (int lf = 0; lf < 2; ++lf)
#pragma unroll
    for (int ks = 0; ks < 4; ++ks)
      a[lf][ks] = *(const bf16x8*)(Qg + (size_t)(lf * 16 + ln) * 128 + ks * 32 + g * 8);
#pragma unroll
  for (int t = 0; t < 2; ++t) {
    float* dst = (t == 0 ? QRW : QRH) + (bhL + l0) * 64;
#pragma unroll
    for (int n = 0; n < 4; ++n) {
      f32x4 acc2[2] = {};
#pragma unroll
      for (int ks = 0; ks < 4; ++ks) {
        int mrow = n * 16 + ln;
        bf16x8 bf = *(const bf16x8*)(sh + t * 16384 + mrow * 256 +
                                     ((ks * 64 + g * 16) ^ ((mrow & 7) << 4)));
#pragma unroll
        for (int lf = 0; lf < 2; ++lf)
          acc2[lf] = __builtin_amdgcn_mfma_f32_16x16x32_bf16(a[lf][ks], bf, acc2[lf], 0, 0, 0);
      }
#pragma unroll
      for (int lf = 0; lf < 2; ++lf)
#pragma unroll
        for (int r = 0; r < 4; ++r)
          dst[(size_t)(lf * 16 + g * 4 + r) * 64 + n * 16 + ln] = acc2[lf][r];
    }
  }
}

// ---------------- kernel 5: fused attention (r14-exact: V in LDS, 16 q/wave) ----------------
// Best-known configuration (67us, VGPR 60, no spill): 16 q/wave x 8 waves,
// swapped QK^T, K+V double-buffered via global_load_lds, P in LDS (r8 layout),
// defer-rescale softmax in exp2 domain, 2 blocks/CU (160K LDS exactly).
// Excluded by measurement: 32 q/wave (needs ~150 VGPR > cap -> spills, r13),
// V-direct-from-global (VGPR budget can't batch loads -> latency-exposed,
// r15/r16), bias-in-GEMM fusion (r17).
__global__ __launch_bounds__(512, 4) void k_attn(const __hip_bfloat16* __restrict__ Qb,
                                                 const __hip_bfloat16* __restrict__ Kb,
                                                 const __hip_bfloat16* __restrict__ Vt,
                                                 const float* __restrict__ QRW,
                                                 const float* __restrict__ QRH,
                                                 float* __restrict__ out) {
  extern __shared__ char smem[];
  char* kb0 = smem;                 // K buf A [64][256B] 16384
  char* kb1 = smem + 16384;         // K buf B 16384
  char* vb0 = smem + 32768;         // V buf A [128][128B] 16384
  char* vb1 = smem + 49152;         // V buf B 16384
  char* pt = smem + 65536;          // P [8 waves][16 q][128B] 16384
                                    // total 81920 B -> 2 blocks/CU (160K exactly)

  int bh = blockIdx.x, qt = blockIdx.y;  // same-bh blocks: ids differ by 64 -> same XCD
  int b = bh >> 2, h = bh & 3;
  int tid = threadIdx.x, lane = tid & 63, wave = tid >> 6;  // wave 0..7
  int g = lane >> 4, ln = lane & 15;
  int q0 = qt * 128;
  size_t bhL = (size_t)bh * 1024;

  // per-lane q (16 q/wave): one-time global->reg loads
  int qloc = wave * 16 + ln;
  int qg = q0 + qloc;
  int cx = qg & 31, rx = qg >> 5;
  bf16x8 qa[4];
  const __hip_bfloat16* qrow = Qb + (bhL + qg) * 128;
#pragma unroll
  for (int ks = 0; ks < 4; ++ks) qa[ks] = *(const bf16x8*)(qrow + ks * 32 + g * 8);
  float wb[2][4];
  const float* wrow = QRW + (bhL + qg) * 64 + (31 - cx) + g * 4;
#pragma unroll
  for (int half = 0; half < 2; ++half)
#pragma unroll
    for (int r = 0; r < 4; ++r) wb[half][r] = wrow[half * 16 + r];
  const float* hptr = QRH + (bhL + qg) * 64 + (31 - rx);

  const char* Kg0 = (const char*)(Kb + bhL * 128);
  const char* Vg0 = (const char*)(Vt + (size_t)bh * 128 * 1024);
  int j3 = lane >> 3, j7 = lane & 7;
  int segv = ((j7 ^ j3) << 4);

  auto STAGE_K = [&](char* kvb, int kt2) {
    const char* Kg = Kg0 + (size_t)kt2 * 64 * 256;
#pragma unroll
    for (int i = 0; i < 2; ++i) {
      int R = (wave * 2 + i) * 4;  // row&7 = 4i + (lane>>4)
      int seg = ((lane & 15) ^ ((i & 1) * 4 + (lane >> 4))) << 4;
      gload16(Kg + (size_t)(R + (lane >> 4)) * 256 + seg, kvb + R * 256);
    }
  };
  auto STAGE_V = [&](char* vtb, int kt2) {
    const char* Vg = Vg0 + (size_t)kt2 * 128;
#pragma unroll
    for (int i = 0; i < 2; ++i) {
      int R = (wave * 2 + i) * 8;
      gload16(Vg + (size_t)(R + j3) * 2048 + segv, vtb + R * 128);
    }
  };

  f32x4 acc[8] = {};
  float mrow = -1e30f, lrow = 0.f;
  char* pw = pt + wave * 2048;

  STAGE_K(kb0, 0);
  STAGE_V(vb0, 0);
  __syncthreads();  // tile 0 ready

  char *kc = kb0, *kn = kb1, *vc = vb0, *vn = vb1;

#pragma unroll 1
  for (int kt = 0; kt < 16; ++kt) {
    if (kt < 15) {
      STAGE_K(kn, kt + 1);
      STAGE_V(vn, kt + 1);
    }
    // hb scalars for this kt (global, L2-hot), issued before QK^T
    float hb0 = hptr[kt * 2], hb1 = hptr[kt * 2 + 1];

    // S^T = K Q^T (log2 domain): s[n][r] = S[key=n*16+g*4+r][q=qloc]
    f32x4 s[4] = {};
    __builtin_amdgcn_s_setprio(1);
#pragma unroll
    for (int ks = 0; ks < 4; ++ks) {
      int kcol = ks * 64 + (g << 4);
#pragma unroll
      for (int n = 0; n < 4; ++n) {
        int krow = n * 16 + ln;
        bf16x8 kf = *(const bf16x8*)(kc + krow * 256 + (kcol ^ ((krow & 7) << 4)));
        s[n] = __builtin_amdgcn_mfma_f32_16x16x32_bf16(kf, qa[ks], s[n], 0, 0, 0);
      }
    }
    __builtin_amdgcn_s_setprio(0);

    // bias + online softmax (defer-rescale, THR=8 in exp2 domain)
#pragma unroll
    for (int n = 0; n < 4; ++n) {
      float hb = (n >> 1) ? hb1 : hb0;
#pragma unroll
      for (int r = 0; r < 4; ++r) s[n][r] += wb[n & 1][r] + hb;
    }
    float mt = s[0][0];
#pragma unroll
    for (int n = 0; n < 4; ++n)
#pragma unroll
      for (int r = 0; r < 4; ++r) mt = fmaxf(mt, s[n][r]);
    mt = fmaxf(mt, __shfl_xor(mt, 16, 64));
    mt = fmaxf(mt, __shfl_xor(mt, 32, 64));
    if (__any(mt > mrow + 8.f)) {
      float mn = fmaxf(mrow, mt);
      float alpha = exp2f(mrow - mn);
      mrow = mn;
      lrow *= alpha;
#pragma unroll
      for (int mf = 0; mf < 8; ++mf) acc[mf] *= alpha;
    }
    float rs = 0.f;
#pragma unroll
    for (int n = 0; n < 4; ++n)
#pragma unroll
      for (int r = 0; r < 4; ++r) {
        s[n][r] = exp2f(s[n][r] - mrow);
        rs += s[n][r];
      }
    rs += __shfl_xor(rs, 16, 64);
    rs += __shfl_xor(rs, 32, 64);
    lrow += rs;

    // write P[q=qloc][key] packed (r8-verified layout)
#pragma unroll
    for (int n = 0; n < 4; ++n) {
      ushort4 pk;
      pk.x = bits_bf16(s[n][0]);
      pk.y = bits_bf16(s[n][1]);
      pk.z = bits_bf16(s[n][2]);
      pk.w = bits_bf16(s[n][3]);
      *(ushort4*)(pw + ln * 128 + ((n * 32 + g * 8) ^ ((ln & 7) << 4))) = pk;
    }
    // PV (transposed): acc[d][q] += V_t . P^T
    __builtin_amdgcn_s_setprio(1);
#pragma unroll
    for (int ks2 = 0; ks2 < 2; ++ks2) {
      int kcb = ks2 * 64 + (g << 4);
      bf16x8 pb = *(const bf16x8*)(pw + ln * 128 + (kcb ^ ((ln & 7) << 4)));
#pragma unroll
      for (int mf = 0; mf < 8; ++mf) {
        int vrow = mf * 16 + ln;
        bf16x8 av = *(const bf16x8*)(vc + vrow * 128 + (kcb ^ ((vrow & 7) << 4)));
        acc[mf] = __builtin_amdgcn_mfma_f32_16x16x32_bf16(av, pb, acc[mf], 0, 0, 0);
      }
    }
    __builtin_amdgcn_s_setprio(0);

    __syncthreads();  // drains next-tile DMA; releases cur buffers
    char* t = kc; kc = kn; kn = t;
    char* t2 = vc; vc = vn; vn = t2;
  }

  // normalize + store (l and acc columns are in-lane)
  float linv = 1.0f / lrow;
#pragma unroll
  for (int mf = 0; mf < 8; ++mf) {
    int dbase = mf * 16 + g * 4;
#pragma unroll
    for (int r = 0; r < 4; ++r) {
      out[((size_t)(b * 512 + h * 128 + dbase + r)) * 1024 + qg] = acc[mf][r] * linv;
    }
  }
}

extern "C" void kernel_launch(void* const* d_in, const int* in_sizes, int n_in,
                              void* d_out, int out_size, void* d_ws, size_t ws_size,
                              hipStream_t stream) {
  const float* fm = (const float*)d_in[0];
  const float* wqk = (const float*)d_in[1];
  const float* wv = (const float*)d_in[2];
  const float* relh = (const float*)d_in[3];
  const float* relw = (const float*)d_in[4];
  float* out = (float*)d_out;
  char* w = (char*)d_ws;

  __hip_bfloat16* fmt = (__hip_bfloat16*)w;                   // 16 MB  [B][L][C]
  __hip_bfloat16* wall = (__hip_bfloat16*)(w + 16777216);     // 1.5 MB [1536][512]
  __hip_bfloat16* Qb = (__hip_bfloat16*)(w + 18350080);       // 16 MB  [B][H][L][D] (scaled*log2e)
  __hip_bfloat16* Kb = (__hip_bfloat16*)(w + 35127296);       // 16 MB  [B][H][L][D]
  __hip_bfloat16* Vt = (__hip_bfloat16*)(w + 51904512);       // 16 MB  [B][H][D][L]
  float* QRW = (float*)(w + 68681728);                        // 16 MB  [B][H][L][64]
  float* QRH = (float*)(w + 85458944);                        // 16 MB  [B][H][L][64]
  __hip_bfloat16* relsb = (__hip_bfloat16*)(w + 102236160);   // 32 KB  [2][64][128]

  hipFuncSetAttribute((const void*)k_attn,
                      hipFuncAttributeMaxDynamicSharedMemorySize, 81920);

  k_convw<<<3136, 256, 0, stream>>>(wqk, wv, relw, relh, wall, relsb);
  k_tfm<<<dim3(16, 8, 16), 256, 0, stream>>>(fm, fmt);
  k_gemm<<<dim3(8, 12, 16), 256, 0, stream>>>(fmt, wall, Qb, Kb, Vt);
  k_bias<<<dim3(8, 64), 256, 0, stream>>>(Qb, relsb, QRW, QRH);
  k_attn<<<dim3(64, 8), 512, 81920, stream>>>(Qb, Kb, Vt, QRW, QRH, out);
}